// Round 1
// baseline (765.741 us; speedup 1.0000x reference)
//
#include <hip/hip_runtime.h>

#define NB 4
#define NT 2048
#define ND 1024
#define NH 16
#define DHD 64

typedef __attribute__((ext_vector_type(4))) float f32x4;
typedef __attribute__((ext_vector_type(8))) short bf16x8;
typedef __attribute__((ext_vector_type(4))) short s16x4;

__device__ __forceinline__ short bf16rn(float f) {
    union { float f; unsigned u; } v; v.f = f;
    unsigned r = v.u + 0x7fffu + ((v.u >> 16) & 1u);
    return (short)(r >> 16);
}

// ---------------- GEMM tile params ----------------
#define BM 128
#define BN 128
#define BK 32

// ---------------- K1: QKV projections ----------------
// Q/K/V[b][h][t][d] (bf16) = x[b*T+t][:] @ W[:, h*64+d]
__global__ __launch_bounds__(256)
void qkv_kernel(const float* __restrict__ x,
                const float* __restrict__ Wq, const float* __restrict__ Wk,
                const float* __restrict__ Wv,
                short* __restrict__ Qo, short* __restrict__ Ko, short* __restrict__ Vo)
{
    const float* W = (blockIdx.z == 0) ? Wq : (blockIdx.z == 1) ? Wk : Wv;
    short* Out = (blockIdx.z == 0) ? Qo : (blockIdx.z == 1) ? Ko : Vo;

    __shared__ short As[BM * BK];   // x tile, bf16, swizzled (row stride 64B)
    __shared__ short Bs[BN * BK];   // W^T tile, bf16, swizzled

    const int tid = threadIdx.x;
    const int lane = tid & 63;
    const int wave = tid >> 6;
    const int row16 = lane & 15;
    const int grp = lane >> 4;
    const int mbase = blockIdx.y * BM;
    const int nbase = blockIdx.x * BN;
    const int wm = (wave >> 1) * 64;
    const int wn = (wave & 1) * 64;

    f32x4 acc[4][4];
#pragma unroll
    for (int i = 0; i < 4; ++i)
#pragma unroll
        for (int j = 0; j < 4; ++j) acc[i][j] = (f32x4)0.0f;

    const int af4 = tid & 7, ar0 = tid >> 3;   // A staging: 8 float4 per 32-f row
    const int bn4 = tid & 31, bkr = tid >> 5;  // B staging: 32 float4 per 128-f row

    for (int kb = 0; kb < ND; kb += BK) {
        __syncthreads();
        // stage A: x[mbase..+127][kb..+31] f32 -> bf16
#pragma unroll
        for (int it = 0; it < 4; ++it) {
            int row = ar0 + it * 32;
            float4 v = *reinterpret_cast<const float4*>(x + (size_t)(mbase + row) * ND + kb + af4 * 4);
            s16x4 hv;
            hv[0] = bf16rn(v.x); hv[1] = bf16rn(v.y); hv[2] = bf16rn(v.z); hv[3] = bf16rn(v.w);
            *reinterpret_cast<s16x4*>(&As[row * 32 + (((af4 >> 1) ^ (row & 3)) * 8) + (af4 & 1) * 4]) = hv;
        }
        // stage B transposed: Bs[n][k] = W[kb+k][nbase+n]
#pragma unroll
        for (int it = 0; it < 4; ++it) {
            int k = bkr + it * 8;
            float4 v = *reinterpret_cast<const float4*>(W + (size_t)(kb + k) * ND + nbase + bn4 * 4);
            float fv[4] = {v.x, v.y, v.z, v.w};
#pragma unroll
            for (int j = 0; j < 4; ++j) {
                int n = bn4 * 4 + j;
                Bs[n * 32 + (((k >> 3) ^ (n & 3)) * 8) + (k & 7)] = bf16rn(fv[j]);
            }
        }
        __syncthreads();

        bf16x8 af[4], bfr[4];
#pragma unroll
        for (int mi = 0; mi < 4; ++mi) {
            int row = wm + mi * 16 + row16;
            af[mi] = *reinterpret_cast<const bf16x8*>(&As[row * 32 + ((grp ^ (row & 3)) * 8)]);
        }
#pragma unroll
        for (int ni = 0; ni < 4; ++ni) {
            int n = wn + ni * 16 + row16;
            bfr[ni] = *reinterpret_cast<const bf16x8*>(&Bs[n * 32 + ((grp ^ (n & 3)) * 8)]);
        }
#pragma unroll
        for (int mi = 0; mi < 4; ++mi)
#pragma unroll
            for (int ni = 0; ni < 4; ++ni)
                acc[mi][ni] = __builtin_amdgcn_mfma_f32_16x16x32_bf16(af[mi], bfr[ni], acc[mi][ni], 0, 0, 0);
    }

    // epilogue: C/D layout row=(lane>>4)*4+r, col=lane&15 -> [b][h][t][d]
#pragma unroll
    for (int mi = 0; mi < 4; ++mi)
#pragma unroll
        for (int ni = 0; ni < 4; ++ni)
#pragma unroll
            for (int r = 0; r < 4; ++r) {
                int rowg = mbase + wm + mi * 16 + grp * 4 + r;
                int colg = nbase + wn + ni * 16 + row16;
                int b = rowg >> 11, t = rowg & (NT - 1);
                int h = colg >> 6, d = colg & 63;
                Out[((size_t)(b * NH + h) * NT + t) * DHD + d] = bf16rn(acc[mi][ni][r]);
            }
}

// ---------------- K2: flash attention ----------------
// grid: (T/64, B*H). 4 waves, each owns 16 q-rows. KV tiles of 64.
__global__ __launch_bounds__(256)
void attn_kernel(const short* __restrict__ Qg, const short* __restrict__ Kg,
                 const short* __restrict__ Vg, short* __restrict__ An)
{
    __shared__ short Ks[64 * 64];     // [kv][d]  swizzled (128B rows)
    __shared__ short Vs[64 * 64];     // [d][kv]  swizzled
    __shared__ short Ps[4 * 16 * 64]; // per-wave P, swizzled

    const int tid = threadIdx.x;
    const int lane = tid & 63;
    const int wave = tid >> 6;
    const int row16 = lane & 15;
    const int grp = lane >> 4;
    const int bh = blockIdx.y;
    const int b = bh >> 4, h = bh & 15;
    const size_t headoff = (size_t)bh * NT * DHD;
    const int qbase = blockIdx.x * 64;

    // Q fragments held in registers for the whole kernel
    bf16x8 qf[2];
    {
        const short* qp = Qg + headoff + (size_t)(qbase + wave * 16 + row16) * DHD + grp * 8;
        qf[0] = *reinterpret_cast<const bf16x8*>(qp);
        qf[1] = *reinterpret_cast<const bf16x8*>(qp + 32);
    }

    float m_run[4], l_run[4];
    f32x4 o_acc[4];
#pragma unroll
    for (int r = 0; r < 4; ++r) { m_run[r] = -1e30f; l_run[r] = 0.f; }
#pragma unroll
    for (int f = 0; f < 4; ++f) o_acc[f] = (f32x4)0.f;

    short* Pw = Ps + wave * (16 * 64);

    for (int kv = 0; kv < NT; kv += 64) {
        __syncthreads();
        // stage K tile: 512 chunks of 8 bf16
#pragma unroll
        for (int it = 0; it < 2; ++it) {
            int chid = tid + it * 256;
            int row = chid >> 3, c8 = chid & 7;
            bf16x8 v = *reinterpret_cast<const bf16x8*>(Kg + headoff + (size_t)(kv + row) * DHD + c8 * 8);
            *reinterpret_cast<bf16x8*>(&Ks[row * 64 + ((c8 ^ (row & 7)) * 8)]) = v;
        }
        // stage V transposed: Vs[d][kvrow]
        {
            int vrow = tid & 63;
            int dc0 = tid >> 6;
#pragma unroll
            for (int it = 0; it < 2; ++it) {
                int dc = dc0 + it * 4;
                bf16x8 v = *reinterpret_cast<const bf16x8*>(Vg + headoff + (size_t)(kv + vrow) * DHD + dc * 8);
#pragma unroll
                for (int e = 0; e < 8; ++e) {
                    int d = dc * 8 + e;
                    Vs[d * 64 + (((vrow >> 3) ^ (d & 7)) * 8) + (vrow & 7)] = v[e];
                }
            }
        }
        __syncthreads();

        // S = Q K^T
        f32x4 s[4];
#pragma unroll
        for (int nf = 0; nf < 4; ++nf) s[nf] = (f32x4)0.f;
#pragma unroll
        for (int c = 0; c < 2; ++c) {
            int c8 = c * 4 + grp;
#pragma unroll
            for (int nf = 0; nf < 4; ++nf) {
                int n = nf * 16 + row16;
                bf16x8 kf = *reinterpret_cast<const bf16x8*>(&Ks[n * 64 + ((c8 ^ (n & 7)) * 8)]);
                s[nf] = __builtin_amdgcn_mfma_f32_16x16x32_bf16(qf[c], kf, s[nf], 0, 0, 0);
            }
        }

        // online softmax (rows r: q-row = grp*4+r; cols across 16 lanes)
        float mt[4], rs[4], corr[4];
#pragma unroll
        for (int r = 0; r < 4; ++r) {
#pragma unroll
            for (int nf = 0; nf < 4; ++nf) s[nf][r] *= 0.125f;
            mt[r] = fmaxf(fmaxf(s[0][r], s[1][r]), fmaxf(s[2][r], s[3][r]));
            mt[r] = fmaxf(mt[r], __shfl_xor(mt[r], 1));
            mt[r] = fmaxf(mt[r], __shfl_xor(mt[r], 2));
            mt[r] = fmaxf(mt[r], __shfl_xor(mt[r], 4));
            mt[r] = fmaxf(mt[r], __shfl_xor(mt[r], 8));
            float mn = fmaxf(m_run[r], mt[r]);
            corr[r] = __expf(m_run[r] - mn);
            m_run[r] = mn;
            rs[r] = 0.f;
#pragma unroll
            for (int nf = 0; nf < 4; ++nf) {
                float p = __expf(s[nf][r] - mn);
                s[nf][r] = p;
                rs[r] += p;
            }
            rs[r] += __shfl_xor(rs[r], 1);
            rs[r] += __shfl_xor(rs[r], 2);
            rs[r] += __shfl_xor(rs[r], 4);
            rs[r] += __shfl_xor(rs[r], 8);
            l_run[r] = l_run[r] * corr[r] + rs[r];
#pragma unroll
            for (int f = 0; f < 4; ++f) o_acc[f][r] *= corr[r];
        }

        // write P (bf16) to per-wave LDS (no barrier needed: wave-private)
#pragma unroll
        for (int nf = 0; nf < 4; ++nf)
#pragma unroll
            for (int r = 0; r < 4; ++r) {
                int prow = grp * 4 + r;
                int pcol = nf * 16 + row16;
                Pw[prow * 64 + (((pcol >> 3) ^ (prow & 7)) * 8) + (pcol & 7)] = bf16rn(s[nf][r]);
            }

        // O += P @ V
#pragma unroll
        for (int c = 0; c < 2; ++c) {
            int c8 = c * 4 + grp;
            bf16x8 pf = *reinterpret_cast<const bf16x8*>(&Pw[row16 * 64 + ((c8 ^ (row16 & 7)) * 8)]);
#pragma unroll
            for (int df = 0; df < 4; ++df) {
                int d = df * 16 + row16;
                bf16x8 vf = *reinterpret_cast<const bf16x8*>(&Vs[d * 64 + ((c8 ^ (d & 7)) * 8)]);
                o_acc[df] = __builtin_amdgcn_mfma_f32_16x16x32_bf16(pf, vf, o_acc[df], 0, 0, 0);
            }
        }
    }

    // epilogue: attn[b*T+t][h*64+d] bf16
#pragma unroll
    for (int df = 0; df < 4; ++df)
#pragma unroll
        for (int r = 0; r < 4; ++r) {
            int t = qbase + wave * 16 + grp * 4 + r;
            int d = df * 16 + row16;
            float val = o_acc[df][r] / l_run[r];
            An[(size_t)(b * NT + t) * ND + h * DHD + d] = bf16rn(val);
        }
}

// ---------------- K3: output projection + bias ----------------
__global__ __launch_bounds__(256)
void outproj_kernel(const short* __restrict__ An, const float* __restrict__ Wo,
                    const float* __restrict__ bo, float* __restrict__ out)
{
    __shared__ short As[BM * BK];
    __shared__ short Bs[BN * BK];

    const int tid = threadIdx.x;
    const int lane = tid & 63;
    const int wave = tid >> 6;
    const int row16 = lane & 15;
    const int grp = lane >> 4;
    const int mbase = blockIdx.y * BM;
    const int nbase = blockIdx.x * BN;
    const int wm = (wave >> 1) * 64;
    const int wn = (wave & 1) * 64;

    f32x4 acc[4][4];
#pragma unroll
    for (int i = 0; i < 4; ++i)
#pragma unroll
        for (int j = 0; j < 4; ++j) acc[i][j] = (f32x4)0.0f;

    const int ach = tid & 3, ar0 = tid >> 2;
    const int bn4 = tid & 31, bkr = tid >> 5;

    for (int kb = 0; kb < ND; kb += BK) {
        __syncthreads();
        // stage A (already bf16): 16B vector copies
#pragma unroll
        for (int it = 0; it < 2; ++it) {
            int row = ar0 + it * 64;
            bf16x8 v = *reinterpret_cast<const bf16x8*>(An + (size_t)(mbase + row) * ND + kb + ach * 8);
            *reinterpret_cast<bf16x8*>(&As[row * 32 + ((ach ^ (row & 3)) * 8)]) = v;
        }
        // stage B transposed
#pragma unroll
        for (int it = 0; it < 4; ++it) {
            int k = bkr + it * 8;
            float4 v = *reinterpret_cast<const float4*>(Wo + (size_t)(kb + k) * ND + nbase + bn4 * 4);
            float fv[4] = {v.x, v.y, v.z, v.w};
#pragma unroll
            for (int j = 0; j < 4; ++j) {
                int n = bn4 * 4 + j;
                Bs[n * 32 + (((k >> 3) ^ (n & 3)) * 8) + (k & 7)] = bf16rn(fv[j]);
            }
        }
        __syncthreads();

        bf16x8 af[4], bfr[4];
#pragma unroll
        for (int mi = 0; mi < 4; ++mi) {
            int row = wm + mi * 16 + row16;
            af[mi] = *reinterpret_cast<const bf16x8*>(&As[row * 32 + ((grp ^ (row & 3)) * 8)]);
        }
#pragma unroll
        for (int ni = 0; ni < 4; ++ni) {
            int n = wn + ni * 16 + row16;
            bfr[ni] = *reinterpret_cast<const bf16x8*>(&Bs[n * 32 + ((grp ^ (n & 3)) * 8)]);
        }
#pragma unroll
        for (int mi = 0; mi < 4; ++mi)
#pragma unroll
            for (int ni = 0; ni < 4; ++ni)
                acc[mi][ni] = __builtin_amdgcn_mfma_f32_16x16x32_bf16(af[mi], bfr[ni], acc[mi][ni], 0, 0, 0);
    }

#pragma unroll
    for (int mi = 0; mi < 4; ++mi)
#pragma unroll
        for (int ni = 0; ni < 4; ++ni)
#pragma unroll
            for (int r = 0; r < 4; ++r) {
                int rowg = mbase + wm + mi * 16 + grp * 4 + r;
                int colg = nbase + wn + ni * 16 + row16;
                out[(size_t)rowg * ND + colg] = acc[mi][ni][r] + bo[colg];
            }
}

extern "C" void kernel_launch(void* const* d_in, const int* in_sizes, int n_in,
                              void* d_out, int out_size, void* d_ws, size_t ws_size,
                              hipStream_t stream) {
    const float* x  = (const float*)d_in[0];
    const float* Wq = (const float*)d_in[1];
    const float* Wk = (const float*)d_in[2];
    const float* Wv = (const float*)d_in[3];
    const float* Wo = (const float*)d_in[4];
    const float* bo = (const float*)d_in[5];
    float* out = (float*)d_out;

    const size_t HSZ = (size_t)NB * NH * NT * DHD;  // 8.39M elems (bf16)
    short* Q  = (short*)d_ws;
    short* K  = Q + HSZ;
    short* V  = K + HSZ;
    short* At = V + HSZ;  // attn, [B*T][D] bf16 — total ws use = 64 MiB

    qkv_kernel<<<dim3(ND / BN, (NB * NT) / BM, 3), dim3(256), 0, stream>>>(x, Wq, Wk, Wv, Q, K, V);
    attn_kernel<<<dim3(NT / 64, NB * NH), dim3(256), 0, stream>>>(Q, K, V, At);
    outproj_kernel<<<dim3(ND / BN, (NB * NT) / BM), dim3(256), 0, stream>>>(At, Wo, bo, out);
}

// Round 2
// 478.796 us; speedup vs baseline: 1.5993x; 1.5993x over previous
//
#include <hip/hip_runtime.h>

#define NB 4
#define NT 2048
#define ND 1024
#define NH 16
#define DHD 64

typedef __attribute__((ext_vector_type(4))) float f32x4;
typedef __attribute__((ext_vector_type(8))) short bf16x8;
typedef __attribute__((ext_vector_type(4))) short s16x4;

__device__ __forceinline__ short bf16rn(float f) {
    union { float f; unsigned u; } v; v.f = f;
    unsigned r = v.u + 0x7fffu + ((v.u >> 16) & 1u);
    return (short)(r >> 16);
}

// packed-convert-friendly cast (compiler emits v_cvt_pk_bf16_f32, RTNE)
__device__ __forceinline__ short tobf(float f) {
    union { __bf16 b; short s; } u; u.b = (__bf16)f; return u.s;
}

// ======================= GEMM kernels (BM=BN=128, BK=64) =======================
// LDS layout (both operands): T[row][64k] bf16, k-chunk c8 (8 bf16 = 16B) stored
// at physical chunk (c8 ^ (row&7)) -> conflict-free ds_read_b128 fragments.

// ---------------- K1: QKV projections ----------------
// Q/K/V[b][h][t][d] (bf16) = x[b*T+t][:] @ W[:, h*64+d]
__global__ __launch_bounds__(256, 2)
void qkv_kernel(const float* __restrict__ x,
                const float* __restrict__ Wq, const float* __restrict__ Wk,
                const float* __restrict__ Wv,
                short* __restrict__ Qo, short* __restrict__ Ko, short* __restrict__ Vo)
{
    const float* W = (blockIdx.z == 0) ? Wq : (blockIdx.z == 1) ? Wk : Wv;
    short* Out = (blockIdx.z == 0) ? Qo : (blockIdx.z == 1) ? Ko : Vo;

    __shared__ short As[128 * 64];
    __shared__ short Bs[128 * 64];

    const int tid = threadIdx.x;
    const int lane = tid & 63;
    const int wave = tid >> 6;
    const int row16 = lane & 15;
    const int grp = lane >> 4;
    const int mbase = blockIdx.y * 128;
    const int nbase = blockIdx.x * 128;
    const int wm = (wave >> 1) * 64;
    const int wn = (wave & 1) * 64;

    f32x4 acc[4][4];
#pragma unroll
    for (int i = 0; i < 4; ++i)
#pragma unroll
        for (int j = 0; j < 4; ++j) acc[i][j] = (f32x4)0.0f;

    for (int kb = 0; kb < ND; kb += 64) {
        __syncthreads();
        // ---- stage A: x[mbase..+127][kb..+63] f32 -> bf16, coalesced reads ----
        {
            const float* src = x + (size_t)mbase * ND + kb;
            float4 v[8];
#pragma unroll
            for (int it = 0; it < 8; ++it)
                v[it] = *reinterpret_cast<const float4*>(src + (size_t)(it * 16 + (tid >> 4)) * ND + (tid & 15) * 4);
            const int c8 = (tid & 15) >> 1, half = tid & 1;
#pragma unroll
            for (int it = 0; it < 8; ++it) {
                int row = it * 16 + (tid >> 4);
                s16x4 hv;
                hv[0] = tobf(v[it].x); hv[1] = tobf(v[it].y); hv[2] = tobf(v[it].z); hv[3] = tobf(v[it].w);
                *reinterpret_cast<s16x4*>(&As[row * 64 + ((c8 ^ (row & 7)) * 8) + half * 4]) = hv;
            }
        }
        // ---- stage B transposed: Bs[n][k] = W[kb+k][nbase+n] ----
        // thread owns rows k = (tid&7)*8 .. +7, cols n0 = ((tid>>3)&31)*4 .. +3
        {
            const float* src = W + (size_t)kb * ND + nbase;
            const int kc = tid & 7;            // k-chunk this thread owns
            const int n0 = ((tid >> 3) & 31) * 4;
            float4 v[8];
#pragma unroll
            for (int s = 0; s < 8; ++s)
                v[s] = *reinterpret_cast<const float4*>(src + (size_t)(kc * 8 + s) * ND + n0);
            const float* vp = reinterpret_cast<const float*>(v);
#pragma unroll
            for (int j = 0; j < 4; ++j) {
                int n = n0 + j;
                bf16x8 hv;
#pragma unroll
                for (int s = 0; s < 8; ++s) hv[s] = tobf(vp[s * 4 + j]);
                *reinterpret_cast<bf16x8*>(&Bs[n * 64 + ((kc ^ (n & 7)) * 8)]) = hv;
            }
        }
        __syncthreads();
        // ---- compute: 32 MFMA / wave ----
#pragma unroll
        for (int kk = 0; kk < 2; ++kk) {
            const int c8 = kk * 4 + grp;
            bf16x8 af[4], bfr[4];
#pragma unroll
            for (int mi = 0; mi < 4; ++mi) {
                int row = wm + mi * 16 + row16;
                af[mi] = *reinterpret_cast<const bf16x8*>(&As[row * 64 + ((c8 ^ (row & 7)) * 8)]);
            }
#pragma unroll
            for (int ni = 0; ni < 4; ++ni) {
                int n = wn + ni * 16 + row16;
                bfr[ni] = *reinterpret_cast<const bf16x8*>(&Bs[n * 64 + ((c8 ^ (n & 7)) * 8)]);
            }
#pragma unroll
            for (int mi = 0; mi < 4; ++mi)
#pragma unroll
                for (int ni = 0; ni < 4; ++ni)
                    acc[mi][ni] = __builtin_amdgcn_mfma_f32_16x16x32_bf16(af[mi], bfr[ni], acc[mi][ni], 0, 0, 0);
        }
    }

    // epilogue: C/D layout row=(lane>>4)*4+r, col=lane&15 -> [b][h][t][d]
#pragma unroll
    for (int mi = 0; mi < 4; ++mi)
#pragma unroll
        for (int ni = 0; ni < 4; ++ni)
#pragma unroll
            for (int r = 0; r < 4; ++r) {
                int rowg = mbase + wm + mi * 16 + grp * 4 + r;
                int colg = nbase + wn + ni * 16 + row16;
                int b = rowg >> 11, t = rowg & (NT - 1);
                int h = colg >> 6, d = colg & 63;
                Out[((size_t)(b * NH + h) * NT + t) * DHD + d] = tobf(acc[mi][ni][r]);
            }
}

// ---------------- K2: flash attention (unchanged from round 0) ----------------
__global__ __launch_bounds__(256)
void attn_kernel(const short* __restrict__ Qg, const short* __restrict__ Kg,
                 const short* __restrict__ Vg, short* __restrict__ An)
{
    __shared__ short Ks[64 * 64];     // [kv][d]  swizzled (128B rows)
    __shared__ short Vs[64 * 64];     // [d][kv]  swizzled
    __shared__ short Ps[4 * 16 * 64]; // per-wave P, swizzled

    const int tid = threadIdx.x;
    const int lane = tid & 63;
    const int wave = tid >> 6;
    const int row16 = lane & 15;
    const int grp = lane >> 4;
    const int bh = blockIdx.y;
    const int b = bh >> 4, h = bh & 15;
    const size_t headoff = (size_t)bh * NT * DHD;
    const int qbase = blockIdx.x * 64;

    bf16x8 qf[2];
    {
        const short* qp = Qg + headoff + (size_t)(qbase + wave * 16 + row16) * DHD + grp * 8;
        qf[0] = *reinterpret_cast<const bf16x8*>(qp);
        qf[1] = *reinterpret_cast<const bf16x8*>(qp + 32);
    }

    float m_run[4], l_run[4];
    f32x4 o_acc[4];
#pragma unroll
    for (int r = 0; r < 4; ++r) { m_run[r] = -1e30f; l_run[r] = 0.f; }
#pragma unroll
    for (int f = 0; f < 4; ++f) o_acc[f] = (f32x4)0.f;

    short* Pw = Ps + wave * (16 * 64);

    for (int kv = 0; kv < NT; kv += 64) {
        __syncthreads();
#pragma unroll
        for (int it = 0; it < 2; ++it) {
            int chid = tid + it * 256;
            int row = chid >> 3, c8 = chid & 7;
            bf16x8 v = *reinterpret_cast<const bf16x8*>(Kg + headoff + (size_t)(kv + row) * DHD + c8 * 8);
            *reinterpret_cast<bf16x8*>(&Ks[row * 64 + ((c8 ^ (row & 7)) * 8)]) = v;
        }
        {
            int vrow = tid & 63;
            int dc0 = tid >> 6;
#pragma unroll
            for (int it = 0; it < 2; ++it) {
                int dc = dc0 + it * 4;
                bf16x8 v = *reinterpret_cast<const bf16x8*>(Vg + headoff + (size_t)(kv + vrow) * DHD + dc * 8);
#pragma unroll
                for (int e = 0; e < 8; ++e) {
                    int d = dc * 8 + e;
                    Vs[d * 64 + (((vrow >> 3) ^ (d & 7)) * 8) + (vrow & 7)] = v[e];
                }
            }
        }
        __syncthreads();

        f32x4 s[4];
#pragma unroll
        for (int nf = 0; nf < 4; ++nf) s[nf] = (f32x4)0.f;
#pragma unroll
        for (int c = 0; c < 2; ++c) {
            int c8 = c * 4 + grp;
#pragma unroll
            for (int nf = 0; nf < 4; ++nf) {
                int n = nf * 16 + row16;
                bf16x8 kf = *reinterpret_cast<const bf16x8*>(&Ks[n * 64 + ((c8 ^ (n & 7)) * 8)]);
                s[nf] = __builtin_amdgcn_mfma_f32_16x16x32_bf16(qf[c], kf, s[nf], 0, 0, 0);
            }
        }

        float mt[4], rs[4], corr[4];
#pragma unroll
        for (int r = 0; r < 4; ++r) {
#pragma unroll
            for (int nf = 0; nf < 4; ++nf) s[nf][r] *= 0.125f;
            mt[r] = fmaxf(fmaxf(s[0][r], s[1][r]), fmaxf(s[2][r], s[3][r]));
            mt[r] = fmaxf(mt[r], __shfl_xor(mt[r], 1));
            mt[r] = fmaxf(mt[r], __shfl_xor(mt[r], 2));
            mt[r] = fmaxf(mt[r], __shfl_xor(mt[r], 4));
            mt[r] = fmaxf(mt[r], __shfl_xor(mt[r], 8));
            float mn = fmaxf(m_run[r], mt[r]);
            corr[r] = __expf(m_run[r] - mn);
            m_run[r] = mn;
            rs[r] = 0.f;
#pragma unroll
            for (int nf = 0; nf < 4; ++nf) {
                float p = __expf(s[nf][r] - mn);
                s[nf][r] = p;
                rs[r] += p;
            }
            rs[r] += __shfl_xor(rs[r], 1);
            rs[r] += __shfl_xor(rs[r], 2);
            rs[r] += __shfl_xor(rs[r], 4);
            rs[r] += __shfl_xor(rs[r], 8);
            l_run[r] = l_run[r] * corr[r] + rs[r];
#pragma unroll
            for (int f = 0; f < 4; ++f) o_acc[f][r] *= corr[r];
        }

#pragma unroll
        for (int nf = 0; nf < 4; ++nf)
#pragma unroll
            for (int r = 0; r < 4; ++r) {
                int prow = grp * 4 + r;
                int pcol = nf * 16 + row16;
                Pw[prow * 64 + (((pcol >> 3) ^ (prow & 7)) * 8) + (pcol & 7)] = bf16rn(s[nf][r]);
            }

#pragma unroll
        for (int c = 0; c < 2; ++c) {
            int c8 = c * 4 + grp;
            bf16x8 pf = *reinterpret_cast<const bf16x8*>(&Pw[row16 * 64 + ((c8 ^ (row16 & 7)) * 8)]);
#pragma unroll
            for (int df = 0; df < 4; ++df) {
                int d = df * 16 + row16;
                bf16x8 vf = *reinterpret_cast<const bf16x8*>(&Vs[d * 64 + ((c8 ^ (d & 7)) * 8)]);
                o_acc[df] = __builtin_amdgcn_mfma_f32_16x16x32_bf16(pf, vf, o_acc[df], 0, 0, 0);
            }
        }
    }

#pragma unroll
    for (int df = 0; df < 4; ++df)
#pragma unroll
        for (int r = 0; r < 4; ++r) {
            int t = qbase + wave * 16 + grp * 4 + r;
            int d = df * 16 + row16;
            float val = o_acc[df][r] / l_run[r];
            An[(size_t)(b * NT + t) * ND + h * DHD + d] = bf16rn(val);
        }
}

// ---------------- K3: output projection + bias ----------------
__global__ __launch_bounds__(256, 2)
void outproj_kernel(const short* __restrict__ An, const float* __restrict__ Wo,
                    const float* __restrict__ bo, float* __restrict__ out)
{
    __shared__ short As[128 * 64];
    __shared__ short Bs[128 * 64];

    const int tid = threadIdx.x;
    const int lane = tid & 63;
    const int wave = tid >> 6;
    const int row16 = lane & 15;
    const int grp = lane >> 4;
    const int mbase = blockIdx.y * 128;
    const int nbase = blockIdx.x * 128;
    const int wm = (wave >> 1) * 64;
    const int wn = (wave & 1) * 64;

    f32x4 acc[4][4];
#pragma unroll
    for (int i = 0; i < 4; ++i)
#pragma unroll
        for (int j = 0; j < 4; ++j) acc[i][j] = (f32x4)0.0f;

    for (int kb = 0; kb < ND; kb += 64) {
        __syncthreads();
        // ---- stage A (already bf16): vector copy with swizzle ----
        {
            const short* src = An + (size_t)mbase * ND + kb;
            const int c8 = tid & 7;
#pragma unroll
            for (int it = 0; it < 4; ++it) {
                int row = it * 32 + (tid >> 3);
                bf16x8 v = *reinterpret_cast<const bf16x8*>(src + (size_t)row * ND + c8 * 8);
                *reinterpret_cast<bf16x8*>(&As[row * 64 + ((c8 ^ (row & 7)) * 8)]) = v;
            }
        }
        // ---- stage B transposed (f32 Wo) ----
        {
            const float* src = Wo + (size_t)kb * ND + nbase;
            const int kc = tid & 7;
            const int n0 = ((tid >> 3) & 31) * 4;
            float4 v[8];
#pragma unroll
            for (int s = 0; s < 8; ++s)
                v[s] = *reinterpret_cast<const float4*>(src + (size_t)(kc * 8 + s) * ND + n0);
            const float* vp = reinterpret_cast<const float*>(v);
#pragma unroll
            for (int j = 0; j < 4; ++j) {
                int n = n0 + j;
                bf16x8 hv;
#pragma unroll
                for (int s = 0; s < 8; ++s) hv[s] = tobf(vp[s * 4 + j]);
                *reinterpret_cast<bf16x8*>(&Bs[n * 64 + ((kc ^ (n & 7)) * 8)]) = hv;
            }
        }
        __syncthreads();
#pragma unroll
        for (int kk = 0; kk < 2; ++kk) {
            const int c8 = kk * 4 + grp;
            bf16x8 af[4], bfr[4];
#pragma unroll
            for (int mi = 0; mi < 4; ++mi) {
                int row = wm + mi * 16 + row16;
                af[mi] = *reinterpret_cast<const bf16x8*>(&As[row * 64 + ((c8 ^ (row & 7)) * 8)]);
            }
#pragma unroll
            for (int ni = 0; ni < 4; ++ni) {
                int n = wn + ni * 16 + row16;
                bfr[ni] = *reinterpret_cast<const bf16x8*>(&Bs[n * 64 + ((c8 ^ (n & 7)) * 8)]);
            }
#pragma unroll
            for (int mi = 0; mi < 4; ++mi)
#pragma unroll
                for (int ni = 0; ni < 4; ++ni)
                    acc[mi][ni] = __builtin_amdgcn_mfma_f32_16x16x32_bf16(af[mi], bfr[ni], acc[mi][ni], 0, 0, 0);
        }
    }

#pragma unroll
    for (int ni = 0; ni < 4; ++ni) {
        int colg = nbase + wn + ni * 16 + row16;
        float bv = bo[colg];
#pragma unroll
        for (int mi = 0; mi < 4; ++mi)
#pragma unroll
            for (int r = 0; r < 4; ++r) {
                int rowg = mbase + wm + mi * 16 + grp * 4 + r;
                out[(size_t)rowg * ND + colg] = acc[mi][ni][r] + bv;
            }
    }
}

extern "C" void kernel_launch(void* const* d_in, const int* in_sizes, int n_in,
                              void* d_out, int out_size, void* d_ws, size_t ws_size,
                              hipStream_t stream) {
    const float* x  = (const float*)d_in[0];
    const float* Wq = (const float*)d_in[1];
    const float* Wk = (const float*)d_in[2];
    const float* Wv = (const float*)d_in[3];
    const float* Wo = (const float*)d_in[4];
    const float* bo = (const float*)d_in[5];
    float* out = (float*)d_out;

    const size_t HSZ = (size_t)NB * NH * NT * DHD;  // 8.39M elems (bf16)
    short* Q  = (short*)d_ws;
    short* K  = Q + HSZ;
    short* V  = K + HSZ;
    short* At = V + HSZ;  // attn, [B*T][D] bf16 — total ws use = 64 MiB

    qkv_kernel<<<dim3(ND / 128, (NB * NT) / 128, 3), dim3(256), 0, stream>>>(x, Wq, Wk, Wv, Q, K, V);
    attn_kernel<<<dim3(NT / 64, NB * NH), dim3(256), 0, stream>>>(Q, K, V, At);
    outproj_kernel<<<dim3(ND / 128, (NB * NT) / 128), dim3(256), 0, stream>>>(At, Wo, bo, out);
}

// Round 4
// 471.140 us; speedup vs baseline: 1.6253x; 1.0163x over previous
//
#include <hip/hip_runtime.h>

#define NB 4
#define NT 2048
#define ND 1024
#define NH 16
#define DHD 64
#define KVB 128

typedef __attribute__((ext_vector_type(4))) float f32x4;
typedef __attribute__((ext_vector_type(8))) short bf16x8;
typedef __attribute__((ext_vector_type(4))) short s16x4;

// packed-convert-friendly cast (compiler emits v_cvt_pk_bf16_f32, RTNE)
__device__ __forceinline__ short tobf(float f) {
    union { __bf16 b; short s; } u; u.b = (__bf16)f; return u.s;
}

// ======================= GEMM kernels (BM=BN=128, BK=64) =======================

// ---------------- K1: QKV projections ----------------
// Q/K/V[b][h][t][d] (bf16) = x[b*T+t][:] @ W[:, h*64+d];  Q pre-scaled by 0.125
__global__ __launch_bounds__(256, 2)
void qkv_kernel(const float* __restrict__ x,
                const float* __restrict__ Wq, const float* __restrict__ Wk,
                const float* __restrict__ Wv,
                short* __restrict__ Qo, short* __restrict__ Ko, short* __restrict__ Vo)
{
    const float* W = (blockIdx.z == 0) ? Wq : (blockIdx.z == 1) ? Wk : Wv;
    short* Out = (blockIdx.z == 0) ? Qo : (blockIdx.z == 1) ? Ko : Vo;
    const float oscale = (blockIdx.z == 0) ? 0.125f : 1.0f;  // fold 1/sqrt(DH) into Q

    __shared__ short As[128 * 64];
    __shared__ short Bs[128 * 64];

    const int tid = threadIdx.x;
    const int lane = tid & 63;
    const int wave = tid >> 6;
    const int row16 = lane & 15;
    const int grp = lane >> 4;
    const int mbase = blockIdx.y * 128;
    const int nbase = blockIdx.x * 128;
    const int wm = (wave >> 1) * 64;
    const int wn = (wave & 1) * 64;

    f32x4 acc[4][4];
#pragma unroll
    for (int i = 0; i < 4; ++i)
#pragma unroll
        for (int j = 0; j < 4; ++j) acc[i][j] = (f32x4)0.0f;

    for (int kb = 0; kb < ND; kb += 64) {
        __syncthreads();
        {
            const float* src = x + (size_t)mbase * ND + kb;
            float4 v[8];
#pragma unroll
            for (int it = 0; it < 8; ++it)
                v[it] = *reinterpret_cast<const float4*>(src + (size_t)(it * 16 + (tid >> 4)) * ND + (tid & 15) * 4);
            const int c8 = (tid & 15) >> 1, half = tid & 1;
#pragma unroll
            for (int it = 0; it < 8; ++it) {
                int row = it * 16 + (tid >> 4);
                s16x4 hv;
                hv[0] = tobf(v[it].x); hv[1] = tobf(v[it].y); hv[2] = tobf(v[it].z); hv[3] = tobf(v[it].w);
                *reinterpret_cast<s16x4*>(&As[row * 64 + ((c8 ^ (row & 7)) * 8) + half * 4]) = hv;
            }
        }
        {
            const float* src = W + (size_t)kb * ND + nbase;
            const int kc = tid & 7;
            const int n0 = ((tid >> 3) & 31) * 4;
            float4 v[8];
#pragma unroll
            for (int s = 0; s < 8; ++s)
                v[s] = *reinterpret_cast<const float4*>(src + (size_t)(kc * 8 + s) * ND + n0);
            const float* vp = reinterpret_cast<const float*>(v);
#pragma unroll
            for (int j = 0; j < 4; ++j) {
                int n = n0 + j;
                bf16x8 hv;
#pragma unroll
                for (int s = 0; s < 8; ++s) hv[s] = tobf(vp[s * 4 + j]);
                *reinterpret_cast<bf16x8*>(&Bs[n * 64 + ((kc ^ (n & 7)) * 8)]) = hv;
            }
        }
        __syncthreads();
#pragma unroll
        for (int kk = 0; kk < 2; ++kk) {
            const int c8 = kk * 4 + grp;
            bf16x8 af[4], bfr[4];
#pragma unroll
            for (int mi = 0; mi < 4; ++mi) {
                int row = wm + mi * 16 + row16;
                af[mi] = *reinterpret_cast<const bf16x8*>(&As[row * 64 + ((c8 ^ (row & 7)) * 8)]);
            }
#pragma unroll
            for (int ni = 0; ni < 4; ++ni) {
                int n = wn + ni * 16 + row16;
                bfr[ni] = *reinterpret_cast<const bf16x8*>(&Bs[n * 64 + ((c8 ^ (n & 7)) * 8)]);
            }
#pragma unroll
            for (int mi = 0; mi < 4; ++mi)
#pragma unroll
                for (int ni = 0; ni < 4; ++ni)
                    acc[mi][ni] = __builtin_amdgcn_mfma_f32_16x16x32_bf16(af[mi], bfr[ni], acc[mi][ni], 0, 0, 0);
        }
    }

#pragma unroll
    for (int mi = 0; mi < 4; ++mi)
#pragma unroll
        for (int ni = 0; ni < 4; ++ni)
#pragma unroll
            for (int r = 0; r < 4; ++r) {
                int rowg = mbase + wm + mi * 16 + grp * 4 + r;
                int colg = nbase + wn + ni * 16 + row16;
                int b = rowg >> 11, t = rowg & (NT - 1);
                int h = colg >> 6, d = colg & 63;
                Out[((size_t)(b * NH + h) * NT + t) * DHD + d] = tobf(acc[mi][ni][r] * oscale);
            }
}

// ---------------- K2: flash attention, KVB=128, round-1 PV structure ----------------
// LDS: Ks [128 kv][64 d]  chunk-swizzled (c8 ^ (row&7))
//      Vs [64 d][128 kv]  chunk-swizzled ((kv>>3) ^ (d&7)), scalar-transposed staging
//      Ps per-wave [16 q][128 kv] chunk-swizzled ((kv>>3) ^ (q&7)), scalar writes
__global__ __launch_bounds__(256)
void attn_kernel(const short* __restrict__ Qg, const short* __restrict__ Kg,
                 const short* __restrict__ Vg, short* __restrict__ An)
{
    __shared__ short Ks[KVB * 64];
    __shared__ short Vs[64 * KVB];
    __shared__ short Ps[4 * 16 * KVB];

    const int tid = threadIdx.x;
    const int lane = tid & 63;
    const int wave = tid >> 6;
    const int row16 = lane & 15;
    const int grp = lane >> 4;
    const int bh = blockIdx.y;
    const int b = bh >> 4, h = bh & 15;
    const size_t headoff = (size_t)bh * NT * DHD;
    const int qbase = blockIdx.x * 64;

    // Q fragments (pre-scaled by 0.125 in qkv)
    bf16x8 qf[2];
    {
        const short* qp = Qg + headoff + (size_t)(qbase + wave * 16 + row16) * DHD + grp * 8;
        qf[0] = *reinterpret_cast<const bf16x8*>(qp);
        qf[1] = *reinterpret_cast<const bf16x8*>(qp + 32);
    }

    float m_run[4], l_run[4];
    f32x4 o_acc[4];
#pragma unroll
    for (int r = 0; r < 4; ++r) { m_run[r] = -1e30f; l_run[r] = 0.f; }
#pragma unroll
    for (int f = 0; f < 4; ++f) o_acc[f] = (f32x4)0.f;

    short* Pw = Ps + wave * (16 * KVB);

    for (int kv = 0; kv < NT; kv += KVB) {
        __syncthreads();
        // ---- stage K tile [128][64]: b128 vector stores, swizzled ----
#pragma unroll
        for (int it = 0; it < 4; ++it) {
            int chid = tid + it * 256;
            int row = chid >> 3, c8 = chid & 7;
            bf16x8 v = *reinterpret_cast<const bf16x8*>(Kg + headoff + (size_t)(kv + row) * DHD + c8 * 8);
            *reinterpret_cast<bf16x8*>(&Ks[row * 64 + ((c8 ^ (row & 7)) * 8)]) = v;
        }
        // ---- stage V transposed [64 d][128 kv]: scalar writes (proven conflict-free) ----
#pragma unroll
        for (int it = 0; it < 4; ++it) {
            int vrow = (tid & 63) + 64 * (it >> 1);
            int dc = (tid >> 6) + 4 * (it & 1);
            bf16x8 v = *reinterpret_cast<const bf16x8*>(Vg + headoff + (size_t)(kv + vrow) * DHD + dc * 8);
#pragma unroll
            for (int e = 0; e < 8; ++e) {
                int d = dc * 8 + e;
                Vs[d * KVB + (((vrow >> 3) ^ (d & 7)) * 8) + (vrow & 7)] = v[e];
            }
        }
        __syncthreads();

        // ---- S = Q K^T  (16 MFMA) ----
        f32x4 s[8];
#pragma unroll
        for (int nf = 0; nf < 8; ++nf) s[nf] = (f32x4)0.f;
        __builtin_amdgcn_s_setprio(1);
#pragma unroll
        for (int c = 0; c < 2; ++c) {
            int c8 = c * 4 + grp;
#pragma unroll
            for (int nf = 0; nf < 8; ++nf) {
                int n = nf * 16 + row16;
                bf16x8 kf = *reinterpret_cast<const bf16x8*>(&Ks[n * 64 + ((c8 ^ (row16 & 7)) * 8)]);
                s[nf] = __builtin_amdgcn_mfma_f32_16x16x32_bf16(qf[c], kf, s[nf], 0, 0, 0);
            }
        }
        __builtin_amdgcn_s_setprio(0);

        // ---- online softmax with defer-max (q-row r = grp*4+r) ----
        float mt[4];
#pragma unroll
        for (int r = 0; r < 4; ++r) {
            float m0 = fmaxf(fmaxf(s[0][r], s[1][r]), fmaxf(s[2][r], s[3][r]));
            float m1 = fmaxf(fmaxf(s[4][r], s[5][r]), fmaxf(s[6][r], s[7][r]));
            float m = fmaxf(m0, m1);
            m = fmaxf(m, __shfl_xor(m, 1));
            m = fmaxf(m, __shfl_xor(m, 2));
            m = fmaxf(m, __shfl_xor(m, 4));
            m = fmaxf(m, __shfl_xor(m, 8));
            mt[r] = m;
        }
        bool ok = (mt[0] - m_run[0] <= 8.f) && (mt[1] - m_run[1] <= 8.f) &&
                  (mt[2] - m_run[2] <= 8.f) && (mt[3] - m_run[3] <= 8.f);
        if (!__all(ok)) {
#pragma unroll
            for (int r = 0; r < 4; ++r) {
                float mn = fmaxf(m_run[r], mt[r]);
                float corr = __expf(m_run[r] - mn);
                m_run[r] = mn;
                l_run[r] *= corr;
#pragma unroll
                for (int f = 0; f < 4; ++f) o_acc[f][r] *= corr;
            }
        }
        float rs[4] = {0.f, 0.f, 0.f, 0.f};
#pragma unroll
        for (int nf = 0; nf < 8; ++nf)
#pragma unroll
            for (int r = 0; r < 4; ++r) {
                float p = __expf(s[nf][r] - m_run[r]);
                s[nf][r] = p;
                rs[r] += p;
            }
#pragma unroll
        for (int r = 0; r < 4; ++r) {
            rs[r] += __shfl_xor(rs[r], 1);
            rs[r] += __shfl_xor(rs[r], 2);
            rs[r] += __shfl_xor(rs[r], 4);
            rs[r] += __shfl_xor(rs[r], 8);
            l_run[r] += rs[r];
        }

        // ---- P (bf16) to per-wave LDS [16 q][128 kv], swizzled (wave-private) ----
#pragma unroll
        for (int nf = 0; nf < 8; ++nf)
#pragma unroll
            for (int r = 0; r < 4; ++r) {
                int prow = grp * 4 + r;
                int pcol = nf * 16 + row16;
                Pw[prow * KVB + (((pcol >> 3) ^ (prow & 7)) * 8) + (pcol & 7)] = tobf(s[nf][r]);
            }

        // ---- O += P @ V  (16 MFMA) ----
#pragma unroll
        for (int c = 0; c < 4; ++c) {
            int c8 = c * 4 + grp;
            bf16x8 pf = *reinterpret_cast<const bf16x8*>(&Pw[row16 * KVB + ((c8 ^ (row16 & 7)) * 8)]);
            __builtin_amdgcn_s_setprio(1);
#pragma unroll
            for (int df = 0; df < 4; ++df) {
                int d = df * 16 + row16;
                bf16x8 vf = *reinterpret_cast<const bf16x8*>(&Vs[d * KVB + ((c8 ^ (d & 7)) * 8)]);
                o_acc[df] = __builtin_amdgcn_mfma_f32_16x16x32_bf16(pf, vf, o_acc[df], 0, 0, 0);
            }
            __builtin_amdgcn_s_setprio(0);
        }
    }

    // ---- epilogue: attn[b*T+t][h*64+d] bf16 ----
#pragma unroll
    for (int df = 0; df < 4; ++df)
#pragma unroll
        for (int r = 0; r < 4; ++r) {
            int t = qbase + wave * 16 + grp * 4 + r;
            int d = df * 16 + row16;
            float val = o_acc[df][r] / l_run[r];
            An[(size_t)(b * NT + t) * ND + h * DHD + d] = tobf(val);
        }
}

// ---------------- K3: output projection + bias ----------------
__global__ __launch_bounds__(256, 2)
void outproj_kernel(const short* __restrict__ An, const float* __restrict__ Wo,
                    const float* __restrict__ bo, float* __restrict__ out)
{
    __shared__ short As[128 * 64];
    __shared__ short Bs[128 * 64];

    const int tid = threadIdx.x;
    const int lane = tid & 63;
    const int wave = tid >> 6;
    const int row16 = lane & 15;
    const int grp = lane >> 4;
    const int mbase = blockIdx.y * 128;
    const int nbase = blockIdx.x * 128;
    const int wm = (wave >> 1) * 64;
    const int wn = (wave & 1) * 64;

    f32x4 acc[4][4];
#pragma unroll
    for (int i = 0; i < 4; ++i)
#pragma unroll
        for (int j = 0; j < 4; ++j) acc[i][j] = (f32x4)0.0f;

    for (int kb = 0; kb < ND; kb += 64) {
        __syncthreads();
        {
            const short* src = An + (size_t)mbase * ND + kb;
            const int c8 = tid & 7;
#pragma unroll
            for (int it = 0; it < 4; ++it) {
                int row = it * 32 + (tid >> 3);
                bf16x8 v = *reinterpret_cast<const bf16x8*>(src + (size_t)row * ND + c8 * 8);
                *reinterpret_cast<bf16x8*>(&As[row * 64 + ((c8 ^ (row & 7)) * 8)]) = v;
            }
        }
        {
            const float* src = Wo + (size_t)kb * ND + nbase;
            const int kc = tid & 7;
            const int n0 = ((tid >> 3) & 31) * 4;
            float4 v[8];
#pragma unroll
            for (int s = 0; s < 8; ++s)
                v[s] = *reinterpret_cast<const float4*>(src + (size_t)(kc * 8 + s) * ND + n0);
            const float* vp = reinterpret_cast<const float*>(v);
#pragma unroll
            for (int j = 0; j < 4; ++j) {
                int n = n0 + j;
                bf16x8 hv;
#pragma unroll
                for (int s = 0; s < 8; ++s) hv[s] = tobf(vp[s * 4 + j]);
                *reinterpret_cast<bf16x8*>(&Bs[n * 64 + ((kc ^ (n & 7)) * 8)]) = hv;
            }
        }
        __syncthreads();
#pragma unroll
        for (int kk = 0; kk < 2; ++kk) {
            const int c8 = kk * 4 + grp;
            bf16x8 af[4], bfr[4];
#pragma unroll
            for (int mi = 0; mi < 4; ++mi) {
                int row = wm + mi * 16 + row16;
                af[mi] = *reinterpret_cast<const bf16x8*>(&As[row * 64 + ((c8 ^ (row & 7)) * 8)]);
            }
#pragma unroll
            for (int ni = 0; ni < 4; ++ni) {
                int n = wn + ni * 16 + row16;
                bfr[ni] = *reinterpret_cast<const bf16x8*>(&Bs[n * 64 + ((c8 ^ (n & 7)) * 8)]);
            }
#pragma unroll
            for (int mi = 0; mi < 4; ++mi)
#pragma unroll
                for (int ni = 0; ni < 4; ++ni)
                    acc[mi][ni] = __builtin_amdgcn_mfma_f32_16x16x32_bf16(af[mi], bfr[ni], acc[mi][ni], 0, 0, 0);
        }
    }

#pragma unroll
    for (int ni = 0; ni < 4; ++ni) {
        int colg = nbase + wn + ni * 16 + row16;
        float bv = bo[colg];
#pragma unroll
        for (int mi = 0; mi < 4; ++mi)
#pragma unroll
            for (int r = 0; r < 4; ++r) {
                int rowg = mbase + wm + mi * 16 + grp * 4 + r;
                out[(size_t)rowg * ND + colg] = acc[mi][ni][r] + bv;
            }
    }
}

extern "C" void kernel_launch(void* const* d_in, const int* in_sizes, int n_in,
                              void* d_out, int out_size, void* d_ws, size_t ws_size,
                              hipStream_t stream) {
    const float* x  = (const float*)d_in[0];
    const float* Wq = (const float*)d_in[1];
    const float* Wk = (const float*)d_in[2];
    const float* Wv = (const float*)d_in[3];
    const float* Wo = (const float*)d_in[4];
    const float* bo = (const float*)d_in[5];
    float* out = (float*)d_out;

    const size_t HSZ = (size_t)NB * NH * NT * DHD;
    short* Q  = (short*)d_ws;
    short* K  = Q + HSZ;
    short* V  = K + HSZ;
    short* At = V + HSZ;

    qkv_kernel<<<dim3(ND / 128, (NB * NT) / 128, 3), dim3(256), 0, stream>>>(x, Wq, Wk, Wv, Q, K, V);
    attn_kernel<<<dim3(NT / 64, NB * NH), dim3(256), 0, stream>>>(Q, K, V, At);
    outproj_kernel<<<dim3(ND / 128, (NB * NT) / 128), dim3(256), 0, stream>>>(At, Wo, bo, out);
}